// Round 9
// baseline (196.331 us; speedup 1.0000x reference)
//
#include <hip/hip_runtime.h>
#include <stdint.h>

typedef unsigned short u16;
typedef __attribute__((ext_vector_type(8))) short bf16x8;
typedef __attribute__((ext_vector_type(4))) float f32x4;
typedef __attribute__((ext_vector_type(4))) unsigned short u16x4;
typedef __attribute__((ext_vector_type(4))) unsigned int u32x4;

#define DEVI static __device__ __forceinline__

// dots*scale folded into Q, with base-2 softmax: exp(s) == exp2(s*log2e)
#define QSCALE (0.125f * 1.4426950408889634f)

DEVI u16 f2bf(float f) {
  union { float f; unsigned int u; } v; v.f = f;
  unsigned int u = v.u + 0x7fffu + ((v.u >> 16) & 1u);
  return (u16)(u >> 16);
}
DEVI void gl16(const void* g, void* l) {
  __builtin_amdgcn_global_load_lds(
      (__attribute__((address_space(1))) void*)g,
      (__attribute__((address_space(3))) void*)l, 16, 0, 0);
}
// packed f32x2 -> bf16x2 (RNE), lo=bf16(a), hi=bf16(b)
DEVI unsigned int cvtpk(float a, float b) {
  unsigned int r;
  asm("v_cvt_pk_bf16_f32 %0, %1, %2" : "=v"(r) : "v"(a), "v"(b));
  return r;
}

// ---------------- K1: LayerNorm -> bf16 ----------------
__global__ __launch_bounds__(256) void k_ln_split(
    const float* __restrict__ x, const float* __restrict__ gamma,
    const float* __restrict__ beta, u16* __restrict__ xh) {
  const int row = blockIdx.x;          // 8192 rows
  const int t = threadIdx.x;           // 256 threads, 4 floats each
  const float4* xr = (const float4*)(x + (size_t)row * 1024);
  float4 v = xr[t];
  float s = v.x + v.y + v.z + v.w;
  float s2 = v.x * v.x + v.y * v.y + v.z * v.z + v.w * v.w;
  #pragma unroll
  for (int m = 1; m < 64; m <<= 1) { s += __shfl_xor(s, m); s2 += __shfl_xor(s2, m); }
  __shared__ float ls[4], ls2[4];
  if ((t & 63) == 0) { ls[t >> 6] = s; ls2[t >> 6] = s2; }
  __syncthreads();
  s = ls[0] + ls[1] + ls[2] + ls[3];
  s2 = ls2[0] + ls2[1] + ls2[2] + ls2[3];
  float mu = s * (1.0f / 1024.0f);
  float var = s2 * (1.0f / 1024.0f) - mu * mu;
  float rstd = rsqrtf(var + 1e-5f);
  float4 g = ((const float4*)gamma)[t];
  float4 b = ((const float4*)beta)[t];
  float xv[4] = {v.x, v.y, v.z, v.w};
  float gg[4] = {g.x, g.y, g.z, g.w};
  float bb[4] = {b.x, b.y, b.z, b.w};
  u16x4 hv;
  #pragma unroll
  for (int i = 0; i < 4; i++) {
    float xn = (xv[i] - mu) * rstd * gg[i] + bb[i];
    hv[i] = f2bf(xn);
  }
  ((u16x4*)xh)[(size_t)row * 256 + t] = hv;
}

// ---------------- K1b: transpose weights, fp32 -> bf16 ----------------
// W [K][N] fp32  ->  Wt [N][K] bf16
__global__ __launch_bounds__(256) void k_wsplit_t(
    const float* __restrict__ W, u16* __restrict__ Wth, int K, int N) {
  __shared__ float tile[32][33];
  const int t = threadIdx.x;
  const int tx = t & 31, ty = t >> 5;  // ty in 0..7
  #pragma unroll
  for (int i = 0; i < 4; i++) {
    int k = blockIdx.y * 32 + ty + i * 8;
    int n = blockIdx.x * 32 + tx;
    tile[ty + i * 8][tx] = W[(size_t)k * N + n];
  }
  __syncthreads();
  #pragma unroll
  for (int i = 0; i < 4; i++) {
    int n = blockIdx.x * 32 + ty + i * 8;   // output row
    int k = blockIdx.y * 32 + tx;           // output col
    Wth[(size_t)n * K + k] = f2bf(tile[tx][ty + i * 8]);
  }
}

// ---------------- K2/K4: bf16 GEMM, BK=64 + XOR-swizzled LDS ------
// C[M x N] = A[M x 1024] * Bt[N x 1024]^T, single product (pure bf16).
// XCD-aware block swizzle: each XCD owns whole bn panels -> B stays in its L2.
// MODE 0: QKV epilogue -- scatter Q (scaled), K, V-transposed, all bf16
// MODE 1: out-proj epilogue -- +bias, fp32 store
template <int MODE>
__global__ __launch_bounds__(256) void k_gemm(
    const u16* __restrict__ Ah, const u16* __restrict__ Bh,
    u16* __restrict__ Qh, u16* __restrict__ Kh, u16* __restrict__ Vth,
    float* __restrict__ Cout, const float* __restrict__ bias) {
  __shared__ u16 sAh[128 * 64];
  __shared__ u16 sBh[128 * 64];
  const int t = threadIdx.x, lane = t & 63, w = t >> 6;
  // XCD swizzle (bijective: grid size divisible by 8)
  const int flat = blockIdx.y * gridDim.x + blockIdx.x;
  const int per = (gridDim.x * gridDim.y) >> 3;
  const int swz = (flat & 7) * per + (flat >> 3);
  const int bm = swz & 63, bn = swz >> 6;
  const int wm = (w >> 1) * 64, wn = (w & 1) * 64;
  const int g = lane >> 4, c = lane & 15;
  const size_t arow0 = (size_t)bm * 128, brow0 = (size_t)bn * 128;

  f32x4 acc[4][4] = {};

  for (int kt = 0; kt < 16; kt++) {
    __syncthreads();
    #pragma unroll
    for (int i = 0; i < 4; i++) {
      int ci = t + i * 256;              // 1024 chunks of 16B per tile
      int r = ci >> 3, cc = ci & 7;
      int cs = cc ^ (r & 7);
      size_t ka = (size_t)kt * 64 + cs * 8;
      gl16(Ah + (arow0 + r) * 1024 + ka, sAh + (size_t)ci * 8);
      gl16(Bh + (brow0 + r) * 1024 + ka, sBh + (size_t)ci * 8);
    }
    __syncthreads();
    #pragma unroll
    for (int ks = 0; ks < 2; ks++) {     // two 32-wide K sub-steps per tile
      bf16x8 afh[4], bfh[4];
      #pragma unroll
      for (int mi = 0; mi < 4; mi++) {
        int row = wm + mi * 16 + c;
        afh[mi] = *(const bf16x8*)(sAh + row * 64 + (((ks * 4 + g) ^ (row & 7)) * 8));
      }
      #pragma unroll
      for (int ni = 0; ni < 4; ni++) {
        int row = wn + ni * 16 + c;
        bfh[ni] = *(const bf16x8*)(sBh + row * 64 + (((ks * 4 + g) ^ (row & 7)) * 8));
      }
      #pragma unroll
      for (int mi = 0; mi < 4; mi++)
        #pragma unroll
        for (int ni = 0; ni < 4; ni++)
          acc[mi][ni] = __builtin_amdgcn_mfma_f32_16x16x32_bf16(afh[mi], bfh[ni], acc[mi][ni], 0, 0, 0);
    }
  }

  if (MODE == 0) {                       // QKV scatter
    #pragma unroll
    for (int mi = 0; mi < 4; mi++) {
      int grow0 = bm * 128 + wm + mi * 16 + g * 4;   // m = b*2048+s
      int b = grow0 >> 11, s0 = grow0 & 2047;
      #pragma unroll
      for (int ni = 0; ni < 4; ni++) {
        int gcol = bn * 128 + wn + ni * 16 + c;       // n in [0,3072)
        int which = gcol >> 10, rem = gcol & 1023;
        int hh = rem >> 6, dd = rem & 63;
        if (which == 2) {                              // V -> transposed [B,H,Dh,S]
          u16x4 hv;
          #pragma unroll
          for (int r = 0; r < 4; r++) hv[r] = f2bf(acc[mi][ni][r]);
          size_t off = ((size_t)((b * 16 + hh) * 64 + dd)) * 2048 + s0;
          *(u16x4*)(Vth + off) = hv;
        } else {                                       // Q or K -> [B,H,S,Dh]
          u16* dh = which ? Kh : Qh;
          float sc = which ? 1.0f : QSCALE;
          #pragma unroll
          for (int r = 0; r < 4; r++) {
            size_t off = ((size_t)(b * 16 + hh) * 2048 + (s0 + r)) * 64 + dd;
            dh[off] = f2bf(acc[mi][ni][r] * sc);
          }
        }
      }
    }
  } else {                               // out-proj: +bias, fp32
    #pragma unroll
    for (int mi = 0; mi < 4; mi++) {
      int grow0 = bm * 128 + wm + mi * 16 + g * 4;
      #pragma unroll
      for (int ni = 0; ni < 4; ni++) {
        int gcol = bn * 128 + wn + ni * 16 + c;
        float bb = bias[gcol];
        #pragma unroll
        for (int r = 0; r < 4; r++)
          Cout[(size_t)(grow0 + r) * 1024 + gcol] = acc[mi][ni][r] + bb;
      }
    }
  }
}

// ---------------- K3: block-causal flash attention (v8) ----------------
// grid (64 b*h, 8); block processes paired q-tiles {15-y, y} = exactly 36
// kv-tiles -> 512 uniform blocks, steady 2 blocks/CU x 8 waves = 4 waves/SIMD
// with zero tail decay. 512 threads, 16 q-rows/wave. Swapped QK^T
// (lane-local softmax), in-register P via cvt_pk + permlane.
// LDS read offsets hoisted out of the kv loop (shared by QK^T and PV).
__global__ __launch_bounds__(512, 4) void k_attn(
    const u16* __restrict__ Qh, const u16* __restrict__ Kh,
    const u16* __restrict__ Vth, u16* __restrict__ Oh) {
  __shared__ u16 lK[2][64 * 64], lV[2][64 * 64];
  const int t = threadIdx.x, lane = t & 63, w = t >> 6;  // 8 waves
  const int bh = blockIdx.x;             // 0..63
  const int b = bh >> 4, h = bh & 15;
  const int g = lane >> 4, c = lane & 15;

  const u16* Kb = Kh + (size_t)bh * 2048 * 64;
  const u16* Vb = Vth + (size_t)bh * 64 * 2048;

  // hoisted LDS read offsets: row = i*16 + c (same formula for K and V reads)
  int roff[4][2];
  #pragma unroll
  for (int i = 0; i < 4; i++)
    #pragma unroll
    for (int ks = 0; ks < 2; ks++) {
      int row = i * 16 + c;
      roff[i][ks] = row * 64 + (((ks * 4 + g) ^ (row & 7)) * 8);
    }

  // staging: 512 threads x 1 chunk each; source pre-swizzled (XOR by row)
  const int ci = t;
  const int r0 = ci >> 3, cc0 = ci & 7;
  const int cs0 = cc0 ^ (r0 & 7);

  for (int half = 0; half < 2; half++) {
    const int qt = half ? blockIdx.y : 15 - blockIdx.y;  // long tile first
    const int qrow0 = qt * 128;
    const int ntiles = ((qt >> 1) + 1) * 4;

    // Q fragments: wave w covers q-rows [qrow0 + w*16, +16); q = c as B-operand
    bf16x8 qf[2];
    {
      const u16* qb = Qh + ((size_t)bh * 2048 + qrow0 + w * 16) * 64;
      #pragma unroll
      for (int ks = 0; ks < 2; ks++)
        qf[ks] = *(const bf16x8*)(qb + (size_t)c * 64 + ks * 32 + g * 8);
    }

    // per-lane softmax state for q-row c
    float mrun = -INFINITY, lrun = 0.f;
    f32x4 o[4] = {};                     // rows q = g*4 + r, col d = di*16+c

    // prologue: stage tile 0 into buffer 0 (prior half's trailing barrier
    // guarantees all waves are done reading the buffers)
    gl16(Kb + (size_t)r0 * 64 + cs0 * 8, lK[0] + (size_t)ci * 8);
    gl16(Vb + (size_t)r0 * 2048 + cs0 * 8, lV[0] + (size_t)ci * 8);
    __syncthreads();

    // prefetch pointers (tile 1), advanced by constant strides
    const u16* gK = Kb + (size_t)(64 + r0) * 64 + cs0 * 8;
    const u16* gV = Vb + (size_t)r0 * 2048 + 64 + cs0 * 8;

    for (int kt = 0; kt < ntiles; kt++) {
      const int cur = kt & 1, nxt = cur ^ 1;
      if (kt + 1 < ntiles) {             // prefetch next tile across compute
        gl16(gK, lK[nxt] + (size_t)ci * 8);  gK += 64 * 64;
        gl16(gV, lV[nxt] + (size_t)ci * 8);  gV += 64;
      }

      // S^T[kv, q] = mfma(A=K, B=Q): lane holds S for q=c, kv=ni*16+g*4+r
      f32x4 s[4] = {};
      __builtin_amdgcn_s_setprio(1);
      #pragma unroll
      for (int ni = 0; ni < 4; ni++)
        #pragma unroll
        for (int ks = 0; ks < 2; ks++) {
          bf16x8 kf = *(const bf16x8*)(lK[cur] + roff[ni][ks]);
          s[ni] = __builtin_amdgcn_mfma_f32_16x16x32_bf16(kf, qf[ks], s[ni], 0, 0, 0);
        }
      __builtin_amdgcn_s_setprio(0);

      // lane-local defer-max check; max3-friendly nesting (16 values, q = c)
      float A0 = fmaxf(fmaxf(s[0][0], s[0][1]), s[0][2]);
      float A1 = fmaxf(fmaxf(s[0][3], s[1][0]), s[1][1]);
      float A2 = fmaxf(fmaxf(s[1][2], s[1][3]), s[2][0]);
      float A3 = fmaxf(fmaxf(s[2][1], s[2][2]), s[2][3]);
      float A4 = fmaxf(fmaxf(s[3][0], s[3][1]), s[3][2]);
      float B0 = fmaxf(fmaxf(A0, A1), A2);
      float tl = fmaxf(fmaxf(fmaxf(B0, A3), A4), s[3][3]);
      if (!__all(tl - mrun <= 8.0f)) {   // rare: first tile or large max jump
        float tm = tl;
        tm = fmaxf(tm, __shfl_xor(tm, 16));
        tm = fmaxf(tm, __shfl_xor(tm, 32));  // row max across the 4 g-lanes
        float mnew = fmaxf(mrun, tm);
        float al = exp2f(mrun - mnew);
        mrun = mnew;
        lrun *= al;
        #pragma unroll
        for (int r = 0; r < 4; r++) {
          float ar = __shfl(al, g * 4 + r);  // alpha for o-row q = g*4+r
          #pragma unroll
          for (int di = 0; di < 4; di++) o[di][r] *= ar;
        }
      }

      // p = exp2(s - m); per-lane partial row-sum; pack+permlane -> PV A-frags
      #pragma unroll
      for (int ni = 0; ni < 4; ni++)
        #pragma unroll
        for (int r = 0; r < 4; r++)
          s[ni][r] = exp2f(s[ni][r] - mrun);
      #pragma unroll
      for (int ni = 0; ni < 4; ni++)
        lrun += (s[ni][0] + s[ni][1]) + (s[ni][2] + s[ni][3]);
      unsigned int Wd[4][2];
      #pragma unroll
      for (int ni = 0; ni < 4; ni++)
        #pragma unroll
        for (int rp = 0; rp < 2; rp++)
          Wd[ni][rp] = cvtpk(s[ni][2 * rp], s[ni][2 * rp + 1]);
      bf16x8 pa[2];
      #pragma unroll
      for (int ks = 0; ks < 2; ks++) {
        unsigned int e0 = Wd[2 * ks][0], f0 = Wd[2 * ks + 1][0];
        unsigned int e1 = Wd[2 * ks][1], f1 = Wd[2 * ks + 1][1];
        asm volatile("v_permlane32_swap_b32 %0, %1" : "+v"(e0), "+v"(f0));
        asm volatile("v_permlane16_swap_b32 %0, %1" : "+v"(e0), "+v"(f0));
        asm volatile("v_permlane32_swap_b32 %0, %1" : "+v"(e1), "+v"(f1));
        asm volatile("v_permlane16_swap_b32 %0, %1" : "+v"(e1), "+v"(f1));
        union { u32x4 u; bf16x8 bv; } cvu;
        cvu.u = (u32x4){e0, e1, f0, f1};
        pa[ks] = cvu.bv;                 // P[q=c, kv=ks*32+g*8+j], j=0..7
      }

      // PV: O += P * V  (V read offsets identical to K's: row = di*16+c)
      __builtin_amdgcn_s_setprio(1);
      #pragma unroll
      for (int di = 0; di < 4; di++)
        #pragma unroll
        for (int ks = 0; ks < 2; ks++) {
          bf16x8 vf = *(const bf16x8*)(lV[cur] + roff[di][ks]);
          o[di] = __builtin_amdgcn_mfma_f32_16x16x32_bf16(pa[ks], vf, o[di], 0, 0, 0);
        }
      __builtin_amdgcn_s_setprio(0);

      // drains the prefetch (issued ~1k cycles ago) and fences buffer reuse
      __syncthreads();
    }

    // epilogue: full row-sum (across g-lanes), normalize, write attnout bf16
    float lf = lrun;
    lf += __shfl_xor(lf, 16);
    lf += __shfl_xor(lf, 32);
    float inv = 1.0f / lf;               // for q = c
    #pragma unroll
    for (int r = 0; r < 4; r++) {
      float ir = __shfl(inv, g * 4 + r); // for q = g*4 + r
      int srow = qrow0 + w * 16 + g * 4 + r;
      size_t rowo = ((size_t)b * 2048 + srow) * 1024 + h * 64;
      #pragma unroll
      for (int di = 0; di < 4; di++)
        Oh[rowo + di * 16 + c] = f2bf(o[di][r] * ir);
    }
  }
}

// ---------------- launch ----------------
extern "C" void kernel_launch(void* const* d_in, const int* in_sizes, int n_in,
                              void* d_out, int out_size, void* d_ws, size_t ws_size,
                              hipStream_t stream) {
  const float* x     = (const float*)d_in[0];
  const float* gamma = (const float*)d_in[1];
  const float* beta  = (const float*)d_in[2];
  const float* Wqkv  = (const float*)d_in[3];
  const float* Wout  = (const float*)d_in[4];
  const float* bout  = (const float*)d_in[5];
  float* out = (float*)d_out;

  char* ws = (char*)d_ws;
  size_t off = 0;
  auto alloc = [&](size_t bytes) { char* p = ws + off; off += (bytes + 255) & ~(size_t)255; return p; };
  const size_t SZ_XN = (size_t)8192 * 1024 * 2;         // 16MB
  const size_t SZ_WQ = (size_t)3072 * 1024 * 2;         // 6MB
  const size_t SZ_WO = (size_t)1024 * 1024 * 2;         // 2MB
  const size_t SZ_QKV = (size_t)4 * 16 * 2048 * 64 * 2; // 16MB
  u16* xnh  = (u16*)alloc(SZ_XN);   // also attnout (bf16) after attention
  u16* wqth = (u16*)alloc(SZ_WQ);
  u16* woth = (u16*)alloc(SZ_WO);
  u16* Qh  = (u16*)alloc(SZ_QKV);
  u16* Kh  = (u16*)alloc(SZ_QKV);
  u16* Vth = (u16*)alloc(SZ_QKV);
  if (off > ws_size) return;  // workspace too small -> fail visibly (poisoned out)

  k_ln_split<<<8192, 256, 0, stream>>>(x, gamma, beta, xnh);
  k_wsplit_t<<<dim3(96, 32), 256, 0, stream>>>(Wqkv, wqth, 1024, 3072);
  k_wsplit_t<<<dim3(32, 32), 256, 0, stream>>>(Wout, woth, 1024, 1024);
  // QKV projection: one pure-bf16 GEMM over all 3072 columns
  k_gemm<0><<<dim3(64, 24), 256, 0, stream>>>(xnh, wqth,
                                              Qh, Kh, Vth, nullptr, nullptr);
  // attnout (bf16) reuses the xn buffer (xn is dead after the QKV GEMM)
  k_attn<<<dim3(64, 8), 512, 0, stream>>>(Qh, Kh, Vth, xnh);
  k_gemm<1><<<dim3(64, 8), 256, 0, stream>>>(xnh, woth,
                                             nullptr, nullptr, nullptr,
                                             out, bout);
}

// Round 10
// 180.859 us; speedup vs baseline: 1.0855x; 1.0855x over previous
//
#include <hip/hip_runtime.h>
#include <stdint.h>

typedef unsigned short u16;
typedef __attribute__((ext_vector_type(8))) short bf16x8;
typedef __attribute__((ext_vector_type(4))) float f32x4;
typedef __attribute__((ext_vector_type(4))) unsigned short u16x4;
typedef __attribute__((ext_vector_type(4))) unsigned int u32x4;

#define DEVI static __device__ __forceinline__

// dots*scale folded into Q, with base-2 softmax: exp(s) == exp2(s*log2e)
#define QSCALE (0.125f * 1.4426950408889634f)

DEVI u16 f2bf(float f) {
  union { float f; unsigned int u; } v; v.f = f;
  unsigned int u = v.u + 0x7fffu + ((v.u >> 16) & 1u);
  return (u16)(u >> 16);
}
DEVI void gl16(const void* g, void* l) {
  __builtin_amdgcn_global_load_lds(
      (__attribute__((address_space(1))) void*)g,
      (__attribute__((address_space(3))) void*)l, 16, 0, 0);
}
// packed f32x2 -> bf16x2 (RNE), lo=bf16(a), hi=bf16(b)
DEVI unsigned int cvtpk(float a, float b) {
  unsigned int r;
  asm("v_cvt_pk_bf16_f32 %0, %1, %2" : "=v"(r) : "v"(a), "v"(b));
  return r;
}

// ---------------- K1: LayerNorm -> bf16 ----------------
__global__ __launch_bounds__(256) void k_ln_split(
    const float* __restrict__ x, const float* __restrict__ gamma,
    const float* __restrict__ beta, u16* __restrict__ xh) {
  const int row = blockIdx.x;          // 8192 rows
  const int t = threadIdx.x;           // 256 threads, 4 floats each
  const float4* xr = (const float4*)(x + (size_t)row * 1024);
  float4 v = xr[t];
  float s = v.x + v.y + v.z + v.w;
  float s2 = v.x * v.x + v.y * v.y + v.z * v.z + v.w * v.w;
  #pragma unroll
  for (int m = 1; m < 64; m <<= 1) { s += __shfl_xor(s, m); s2 += __shfl_xor(s2, m); }
  __shared__ float ls[4], ls2[4];
  if ((t & 63) == 0) { ls[t >> 6] = s; ls2[t >> 6] = s2; }
  __syncthreads();
  s = ls[0] + ls[1] + ls[2] + ls[3];
  s2 = ls2[0] + ls2[1] + ls2[2] + ls2[3];
  float mu = s * (1.0f / 1024.0f);
  float var = s2 * (1.0f / 1024.0f) - mu * mu;
  float rstd = rsqrtf(var + 1e-5f);
  float4 g = ((const float4*)gamma)[t];
  float4 b = ((const float4*)beta)[t];
  float xv[4] = {v.x, v.y, v.z, v.w};
  float gg[4] = {g.x, g.y, g.z, g.w};
  float bb[4] = {b.x, b.y, b.z, b.w};
  u16x4 hv;
  #pragma unroll
  for (int i = 0; i < 4; i++) {
    float xn = (xv[i] - mu) * rstd * gg[i] + bb[i];
    hv[i] = f2bf(xn);
  }
  ((u16x4*)xh)[(size_t)row * 256 + t] = hv;
}

// ---------------- K1b: transpose weights, fp32 -> bf16 ----------------
// W [K][N] fp32  ->  Wt [N][K] bf16
__global__ __launch_bounds__(256) void k_wsplit_t(
    const float* __restrict__ W, u16* __restrict__ Wth, int K, int N) {
  __shared__ float tile[32][33];
  const int t = threadIdx.x;
  const int tx = t & 31, ty = t >> 5;  // ty in 0..7
  #pragma unroll
  for (int i = 0; i < 4; i++) {
    int k = blockIdx.y * 32 + ty + i * 8;
    int n = blockIdx.x * 32 + tx;
    tile[ty + i * 8][tx] = W[(size_t)k * N + n];
  }
  __syncthreads();
  #pragma unroll
  for (int i = 0; i < 4; i++) {
    int n = blockIdx.x * 32 + ty + i * 8;   // output row
    int k = blockIdx.y * 32 + tx;           // output col
    Wth[(size_t)n * K + k] = f2bf(tile[tx][ty + i * 8]);
  }
}

// ---------------- K2/K4: bf16 GEMM, BK=64 + XOR-swizzled LDS ------
// C[M x N] = A[M x 1024] * Bt[N x 1024]^T, single product (pure bf16).
// Identity block mapping: bm = blockIdx.x (fast) -> XCD i only ever touches
// bm = i mod 8, a 2MB A-slice that stays L2-resident across all bn rounds.
// (R9's XCD swizzle broke this: FETCH 28 -> 200 MB. Do not re-add.)
// MODE 0: QKV epilogue -- scatter Q (scaled), K, V-transposed, all bf16
// MODE 1: out-proj epilogue -- +bias, fp32 store
template <int MODE>
__global__ __launch_bounds__(256) void k_gemm(
    const u16* __restrict__ Ah, const u16* __restrict__ Bh,
    u16* __restrict__ Qh, u16* __restrict__ Kh, u16* __restrict__ Vth,
    float* __restrict__ Cout, const float* __restrict__ bias) {
  __shared__ u16 sAh[128 * 64];
  __shared__ u16 sBh[128 * 64];
  const int t = threadIdx.x, lane = t & 63, w = t >> 6;
  const int bm = blockIdx.x, bn = blockIdx.y;
  const int wm = (w >> 1) * 64, wn = (w & 1) * 64;
  const int g = lane >> 4, c = lane & 15;
  const size_t arow0 = (size_t)bm * 128, brow0 = (size_t)bn * 128;

  f32x4 acc[4][4] = {};

  for (int kt = 0; kt < 16; kt++) {
    __syncthreads();
    #pragma unroll
    for (int i = 0; i < 4; i++) {
      int ci = t + i * 256;              // 1024 chunks of 16B per tile
      int r = ci >> 3, cc = ci & 7;
      int cs = cc ^ (r & 7);
      size_t ka = (size_t)kt * 64 + cs * 8;
      gl16(Ah + (arow0 + r) * 1024 + ka, sAh + (size_t)ci * 8);
      gl16(Bh + (brow0 + r) * 1024 + ka, sBh + (size_t)ci * 8);
    }
    __syncthreads();
    #pragma unroll
    for (int ks = 0; ks < 2; ks++) {     // two 32-wide K sub-steps per tile
      bf16x8 afh[4], bfh[4];
      #pragma unroll
      for (int mi = 0; mi < 4; mi++) {
        int row = wm + mi * 16 + c;
        afh[mi] = *(const bf16x8*)(sAh + row * 64 + (((ks * 4 + g) ^ (row & 7)) * 8));
      }
      #pragma unroll
      for (int ni = 0; ni < 4; ni++) {
        int row = wn + ni * 16 + c;
        bfh[ni] = *(const bf16x8*)(sBh + row * 64 + (((ks * 4 + g) ^ (row & 7)) * 8));
      }
      #pragma unroll
      for (int mi = 0; mi < 4; mi++)
        #pragma unroll
        for (int ni = 0; ni < 4; ni++)
          acc[mi][ni] = __builtin_amdgcn_mfma_f32_16x16x32_bf16(afh[mi], bfh[ni], acc[mi][ni], 0, 0, 0);
    }
  }

  if (MODE == 0) {                       // QKV scatter
    #pragma unroll
    for (int mi = 0; mi < 4; mi++) {
      int grow0 = bm * 128 + wm + mi * 16 + g * 4;   // m = b*2048+s
      int b = grow0 >> 11, s0 = grow0 & 2047;
      #pragma unroll
      for (int ni = 0; ni < 4; ni++) {
        int gcol = bn * 128 + wn + ni * 16 + c;       // n in [0,3072)
        int which = gcol >> 10, rem = gcol & 1023;
        int hh = rem >> 6, dd = rem & 63;
        if (which == 2) {                              // V -> transposed [B,H,Dh,S]
          u16x4 hv;
          #pragma unroll
          for (int r = 0; r < 4; r++) hv[r] = f2bf(acc[mi][ni][r]);
          size_t off = ((size_t)((b * 16 + hh) * 64 + dd)) * 2048 + s0;
          *(u16x4*)(Vth + off) = hv;
        } else {                                       // Q or K -> [B,H,S,Dh]
          u16* dh = which ? Kh : Qh;
          float sc = which ? 1.0f : QSCALE;
          #pragma unroll
          for (int r = 0; r < 4; r++) {
            size_t off = ((size_t)(b * 16 + hh) * 2048 + (s0 + r)) * 64 + dd;
            dh[off] = f2bf(acc[mi][ni][r] * sc);
          }
        }
      }
    }
  } else {                               // out-proj: +bias, fp32
    #pragma unroll
    for (int mi = 0; mi < 4; mi++) {
      int grow0 = bm * 128 + wm + mi * 16 + g * 4;
      #pragma unroll
      for (int ni = 0; ni < 4; ni++) {
        int gcol = bn * 128 + wn + ni * 16 + c;
        float bb = bias[gcol];
        #pragma unroll
        for (int r = 0; r < 4; r++)
          Cout[(size_t)(grow0 + r) * 1024 + gcol] = acc[mi][ni][r] + bb;
      }
    }
  }
}

// ---------------- K3: block-causal flash attention (v8) ----------------
// grid (64 b*h, 8); block processes paired q-tiles {15-y, y} = exactly 36
// kv-tiles -> 512 uniform blocks, steady 2 blocks/CU x 8 waves = 4 waves/SIMD
// with zero tail decay. 512 threads, 16 q-rows/wave. Swapped QK^T
// (lane-local softmax), in-register P via cvt_pk + permlane.
// LDS read offsets hoisted out of the kv loop (shared by QK^T and PV).
__global__ __launch_bounds__(512, 4) void k_attn(
    const u16* __restrict__ Qh, const u16* __restrict__ Kh,
    const u16* __restrict__ Vth, u16* __restrict__ Oh) {
  __shared__ u16 lK[2][64 * 64], lV[2][64 * 64];
  const int t = threadIdx.x, lane = t & 63, w = t >> 6;  // 8 waves
  const int bh = blockIdx.x;             // 0..63
  const int b = bh >> 4, h = bh & 15;
  const int g = lane >> 4, c = lane & 15;

  const u16* Kb = Kh + (size_t)bh * 2048 * 64;
  const u16* Vb = Vth + (size_t)bh * 64 * 2048;

  // hoisted LDS read offsets: row = i*16 + c (same formula for K and V reads)
  int roff[4][2];
  #pragma unroll
  for (int i = 0; i < 4; i++)
    #pragma unroll
    for (int ks = 0; ks < 2; ks++) {
      int row = i * 16 + c;
      roff[i][ks] = row * 64 + (((ks * 4 + g) ^ (row & 7)) * 8);
    }

  // staging: 512 threads x 1 chunk each; source pre-swizzled (XOR by row)
  const int ci = t;
  const int r0 = ci >> 3, cc0 = ci & 7;
  const int cs0 = cc0 ^ (r0 & 7);

  for (int half = 0; half < 2; half++) {
    const int qt = half ? blockIdx.y : 15 - blockIdx.y;  // long tile first
    const int qrow0 = qt * 128;
    const int ntiles = ((qt >> 1) + 1) * 4;

    // Q fragments: wave w covers q-rows [qrow0 + w*16, +16); q = c as B-operand
    bf16x8 qf[2];
    {
      const u16* qb = Qh + ((size_t)bh * 2048 + qrow0 + w * 16) * 64;
      #pragma unroll
      for (int ks = 0; ks < 2; ks++)
        qf[ks] = *(const bf16x8*)(qb + (size_t)c * 64 + ks * 32 + g * 8);
    }

    // per-lane softmax state for q-row c
    float mrun = -INFINITY, lrun = 0.f;
    f32x4 o[4] = {};                     // rows q = g*4 + r, col d = di*16+c

    // prologue: stage tile 0 into buffer 0 (prior half's trailing barrier
    // guarantees all waves are done reading the buffers)
    gl16(Kb + (size_t)r0 * 64 + cs0 * 8, lK[0] + (size_t)ci * 8);
    gl16(Vb + (size_t)r0 * 2048 + cs0 * 8, lV[0] + (size_t)ci * 8);
    __syncthreads();

    // prefetch pointers (tile 1), advanced by constant strides
    const u16* gK = Kb + (size_t)(64 + r0) * 64 + cs0 * 8;
    const u16* gV = Vb + (size_t)r0 * 2048 + 64 + cs0 * 8;

    for (int kt = 0; kt < ntiles; kt++) {
      const int cur = kt & 1, nxt = cur ^ 1;
      if (kt + 1 < ntiles) {             // prefetch next tile across compute
        gl16(gK, lK[nxt] + (size_t)ci * 8);  gK += 64 * 64;
        gl16(gV, lV[nxt] + (size_t)ci * 8);  gV += 64;
      }

      // S^T[kv, q] = mfma(A=K, B=Q): lane holds S for q=c, kv=ni*16+g*4+r
      f32x4 s[4] = {};
      __builtin_amdgcn_s_setprio(1);
      #pragma unroll
      for (int ni = 0; ni < 4; ni++)
        #pragma unroll
        for (int ks = 0; ks < 2; ks++) {
          bf16x8 kf = *(const bf16x8*)(lK[cur] + roff[ni][ks]);
          s[ni] = __builtin_amdgcn_mfma_f32_16x16x32_bf16(kf, qf[ks], s[ni], 0, 0, 0);
        }
      __builtin_amdgcn_s_setprio(0);

      // lane-local defer-max check; max3-friendly nesting (16 values, q = c)
      float A0 = fmaxf(fmaxf(s[0][0], s[0][1]), s[0][2]);
      float A1 = fmaxf(fmaxf(s[0][3], s[1][0]), s[1][1]);
      float A2 = fmaxf(fmaxf(s[1][2], s[1][3]), s[2][0]);
      float A3 = fmaxf(fmaxf(s[2][1], s[2][2]), s[2][3]);
      float A4 = fmaxf(fmaxf(s[3][0], s[3][1]), s[3][2]);
      float B0 = fmaxf(fmaxf(A0, A1), A2);
      float tl = fmaxf(fmaxf(fmaxf(B0, A3), A4), s[3][3]);
      if (!__all(tl - mrun <= 8.0f)) {   // rare: first tile or large max jump
        float tm = tl;
        tm = fmaxf(tm, __shfl_xor(tm, 16));
        tm = fmaxf(tm, __shfl_xor(tm, 32));  // row max across the 4 g-lanes
        float mnew = fmaxf(mrun, tm);
        float al = exp2f(mrun - mnew);
        mrun = mnew;
        lrun *= al;
        #pragma unroll
        for (int r = 0; r < 4; r++) {
          float ar = __shfl(al, g * 4 + r);  // alpha for o-row q = g*4+r
          #pragma unroll
          for (int di = 0; di < 4; di++) o[di][r] *= ar;
        }
      }

      // p = exp2(s - m); per-lane partial row-sum; pack+permlane -> PV A-frags
      #pragma unroll
      for (int ni = 0; ni < 4; ni++)
        #pragma unroll
        for (int r = 0; r < 4; r++)
          s[ni][r] = exp2f(s[ni][r] - mrun);
      #pragma unroll
      for (int ni = 0; ni < 4; ni++)
        lrun += (s[ni][0] + s[ni][1]) + (s[ni][2] + s[ni][3]);
      unsigned int Wd[4][2];
      #pragma unroll
      for (int ni = 0; ni < 4; ni++)
        #pragma unroll
        for (int rp = 0; rp < 2; rp++)
          Wd[ni][rp] = cvtpk(s[ni][2 * rp], s[ni][2 * rp + 1]);
      bf16x8 pa[2];
      #pragma unroll
      for (int ks = 0; ks < 2; ks++) {
        unsigned int e0 = Wd[2 * ks][0], f0 = Wd[2 * ks + 1][0];
        unsigned int e1 = Wd[2 * ks][1], f1 = Wd[2 * ks + 1][1];
        asm volatile("v_permlane32_swap_b32 %0, %1" : "+v"(e0), "+v"(f0));
        asm volatile("v_permlane16_swap_b32 %0, %1" : "+v"(e0), "+v"(f0));
        asm volatile("v_permlane32_swap_b32 %0, %1" : "+v"(e1), "+v"(f1));
        asm volatile("v_permlane16_swap_b32 %0, %1" : "+v"(e1), "+v"(f1));
        union { u32x4 u; bf16x8 bv; } cvu;
        cvu.u = (u32x4){e0, e1, f0, f1};
        pa[ks] = cvu.bv;                 // P[q=c, kv=ks*32+g*8+j], j=0..7
      }

      // PV: O += P * V  (V read offsets identical to K's: row = di*16+c)
      __builtin_amdgcn_s_setprio(1);
      #pragma unroll
      for (int di = 0; di < 4; di++)
        #pragma unroll
        for (int ks = 0; ks < 2; ks++) {
          bf16x8 vf = *(const bf16x8*)(lV[cur] + roff[di][ks]);
          o[di] = __builtin_amdgcn_mfma_f32_16x16x32_bf16(pa[ks], vf, o[di], 0, 0, 0);
        }
      __builtin_amdgcn_s_setprio(0);

      // drains the prefetch (issued ~1k cycles ago) and fences buffer reuse
      __syncthreads();
    }

    // epilogue: full row-sum (across g-lanes), normalize, write attnout bf16
    float lf = lrun;
    lf += __shfl_xor(lf, 16);
    lf += __shfl_xor(lf, 32);
    float inv = 1.0f / lf;               // for q = c
    #pragma unroll
    for (int r = 0; r < 4; r++) {
      float ir = __shfl(inv, g * 4 + r); // for q = g*4 + r
      int srow = qrow0 + w * 16 + g * 4 + r;
      size_t rowo = ((size_t)b * 2048 + srow) * 1024 + h * 64;
      #pragma unroll
      for (int di = 0; di < 4; di++)
        Oh[rowo + di * 16 + c] = f2bf(o[di][r] * ir);
    }
  }
}

// ---------------- launch ----------------
extern "C" void kernel_launch(void* const* d_in, const int* in_sizes, int n_in,
                              void* d_out, int out_size, void* d_ws, size_t ws_size,
                              hipStream_t stream) {
  const float* x     = (const float*)d_in[0];
  const float* gamma = (const float*)d_in[1];
  const float* beta  = (const float*)d_in[2];
  const float* Wqkv  = (const float*)d_in[3];
  const float* Wout  = (const float*)d_in[4];
  const float* bout  = (const float*)d_in[5];
  float* out = (float*)d_out;

  char* ws = (char*)d_ws;
  size_t off = 0;
  auto alloc = [&](size_t bytes) { char* p = ws + off; off += (bytes + 255) & ~(size_t)255; return p; };
  const size_t SZ_XN = (size_t)8192 * 1024 * 2;         // 16MB
  const size_t SZ_WQ = (size_t)3072 * 1024 * 2;         // 6MB
  const size_t SZ_WO = (size_t)1024 * 1024 * 2;         // 2MB
  const size_t SZ_QKV = (size_t)4 * 16 * 2048 * 64 * 2; // 16MB
  u16* xnh  = (u16*)alloc(SZ_XN);   // also attnout (bf16) after attention
  u16* wqth = (u16*)alloc(SZ_WQ);
  u16* woth = (u16*)alloc(SZ_WO);
  u16* Qh  = (u16*)alloc(SZ_QKV);
  u16* Kh  = (u16*)alloc(SZ_QKV);
  u16* Vth = (u16*)alloc(SZ_QKV);
  if (off > ws_size) return;  // workspace too small -> fail visibly (poisoned out)

  k_ln_split<<<8192, 256, 0, stream>>>(x, gamma, beta, xnh);
  k_wsplit_t<<<dim3(96, 32), 256, 0, stream>>>(Wqkv, wqth, 1024, 3072);
  k_wsplit_t<<<dim3(32, 32), 256, 0, stream>>>(Wout, woth, 1024, 1024);
  // QKV projection: one pure-bf16 GEMM over all 3072 columns
  k_gemm<0><<<dim3(64, 24), 256, 0, stream>>>(xnh, wqth,
                                              Qh, Kh, Vth, nullptr, nullptr);
  // attnout (bf16) reuses the xn buffer (xn is dead after the QKV GEMM)
  k_attn<<<dim3(64, 8), 512, 0, stream>>>(Qh, Kh, Vth, xnh);
  k_gemm<1><<<dim3(64, 8), 256, 0, stream>>>(xnh, woth,
                                             nullptr, nullptr, nullptr,
                                             out, bout);
}

// Round 11
// 163.881 us; speedup vs baseline: 1.1980x; 1.1036x over previous
//
#include <hip/hip_runtime.h>
#include <stdint.h>

typedef unsigned short u16;
typedef __attribute__((ext_vector_type(8))) short bf16x8;
typedef __attribute__((ext_vector_type(4))) float f32x4;
typedef __attribute__((ext_vector_type(4))) unsigned short u16x4;
typedef __attribute__((ext_vector_type(4))) unsigned int u32x4;

#define DEVI static __device__ __forceinline__

// dots*scale folded into Q, with base-2 softmax: exp(s) == exp2(s*log2e)
#define QSCALE (0.125f * 1.4426950408889634f)

DEVI u16 f2bf(float f) {
  union { float f; unsigned int u; } v; v.f = f;
  unsigned int u = v.u + 0x7fffu + ((v.u >> 16) & 1u);
  return (u16)(u >> 16);
}
DEVI void gl16(const void* g, void* l) {
  __builtin_amdgcn_global_load_lds(
      (__attribute__((address_space(1))) void*)g,
      (__attribute__((address_space(3))) void*)l, 16, 0, 0);
}
// packed f32x2 -> bf16x2 (RNE), lo=bf16(a), hi=bf16(b)
DEVI unsigned int cvtpk(float a, float b) {
  unsigned int r;
  asm("v_cvt_pk_bf16_f32 %0, %1, %2" : "=v"(r) : "v"(a), "v"(b));
  return r;
}
// raw v_exp_f32 (flushes f32 denormal results -- fine: such P vanish in the
// bf16 P / fp32 sum anyway). s_nop 0 covers the trans->use wait state.
DEVI float fexp2(float x) {
  float r;
  asm("v_exp_f32 %0, %1\n\ts_nop 0" : "=v"(r) : "v"(x));
  return r;
}
DEVI float fmax4(f32x4 v) {
  return fmaxf(fmaxf(v[0], v[1]), fmaxf(v[2], v[3]));
}

// ---------------- K1: LayerNorm -> bf16 ----------------
__global__ __launch_bounds__(256) void k_ln_split(
    const float* __restrict__ x, const float* __restrict__ gamma,
    const float* __restrict__ beta, u16* __restrict__ xh) {
  const int row = blockIdx.x;          // 8192 rows
  const int t = threadIdx.x;           // 256 threads, 4 floats each
  const float4* xr = (const float4*)(x + (size_t)row * 1024);
  float4 v = xr[t];
  float s = v.x + v.y + v.z + v.w;
  float s2 = v.x * v.x + v.y * v.y + v.z * v.z + v.w * v.w;
  #pragma unroll
  for (int m = 1; m < 64; m <<= 1) { s += __shfl_xor(s, m); s2 += __shfl_xor(s2, m); }
  __shared__ float ls[4], ls2[4];
  if ((t & 63) == 0) { ls[t >> 6] = s; ls2[t >> 6] = s2; }
  __syncthreads();
  s = ls[0] + ls[1] + ls[2] + ls[3];
  s2 = ls2[0] + ls2[1] + ls2[2] + ls2[3];
  float mu = s * (1.0f / 1024.0f);
  float var = s2 * (1.0f / 1024.0f) - mu * mu;
  float rstd = rsqrtf(var + 1e-5f);
  float4 g = ((const float4*)gamma)[t];
  float4 b = ((const float4*)beta)[t];
  float xv[4] = {v.x, v.y, v.z, v.w};
  float gg[4] = {g.x, g.y, g.z, g.w};
  float bb[4] = {b.x, b.y, b.z, b.w};
  u16x4 hv;
  #pragma unroll
  for (int i = 0; i < 4; i++) {
    float xn = (xv[i] - mu) * rstd * gg[i] + bb[i];
    hv[i] = f2bf(xn);
  }
  ((u16x4*)xh)[(size_t)row * 256 + t] = hv;
}

// ---------------- K1b: transpose weights, fp32 -> bf16 ----------------
__global__ __launch_bounds__(256) void k_wsplit_t(
    const float* __restrict__ W, u16* __restrict__ Wth, int K, int N) {
  __shared__ float tile[32][33];
  const int t = threadIdx.x;
  const int tx = t & 31, ty = t >> 5;  // ty in 0..7
  #pragma unroll
  for (int i = 0; i < 4; i++) {
    int k = blockIdx.y * 32 + ty + i * 8;
    int n = blockIdx.x * 32 + tx;
    tile[ty + i * 8][tx] = W[(size_t)k * N + n];
  }
  __syncthreads();
  #pragma unroll
  for (int i = 0; i < 4; i++) {
    int n = blockIdx.x * 32 + ty + i * 8;   // output row
    int k = blockIdx.y * 32 + tx;           // output col
    Wth[(size_t)n * K + k] = f2bf(tile[tx][ty + i * 8]);
  }
}

// ---------------- K2/K4: bf16 GEMM, BK=64 + XOR-swizzled LDS ------
// Identity block mapping: bm = blockIdx.x (fast) -> XCD i only ever touches
// bm = i mod 8, a 2MB A-slice that stays L2-resident across all bn rounds.
// (R9's XCD swizzle broke this: FETCH 28 -> 200 MB. Do not re-add.)
template <int MODE>
__global__ __launch_bounds__(256) void k_gemm(
    const u16* __restrict__ Ah, const u16* __restrict__ Bh,
    u16* __restrict__ Qh, u16* __restrict__ Kh, u16* __restrict__ Vth,
    float* __restrict__ Cout, const float* __restrict__ bias) {
  __shared__ u16 sAh[128 * 64];
  __shared__ u16 sBh[128 * 64];
  const int t = threadIdx.x, lane = t & 63, w = t >> 6;
  const int bm = blockIdx.x, bn = blockIdx.y;
  const int wm = (w >> 1) * 64, wn = (w & 1) * 64;
  const int g = lane >> 4, c = lane & 15;
  const size_t arow0 = (size_t)bm * 128, brow0 = (size_t)bn * 128;

  f32x4 acc[4][4] = {};

  for (int kt = 0; kt < 16; kt++) {
    __syncthreads();
    #pragma unroll
    for (int i = 0; i < 4; i++) {
      int ci = t + i * 256;              // 1024 chunks of 16B per tile
      int r = ci >> 3, cc = ci & 7;
      int cs = cc ^ (r & 7);
      size_t ka = (size_t)kt * 64 + cs * 8;
      gl16(Ah + (arow0 + r) * 1024 + ka, sAh + (size_t)ci * 8);
      gl16(Bh + (brow0 + r) * 1024 + ka, sBh + (size_t)ci * 8);
    }
    __syncthreads();
    #pragma unroll
    for (int ks = 0; ks < 2; ks++) {     // two 32-wide K sub-steps per tile
      bf16x8 afh[4], bfh[4];
      #pragma unroll
      for (int mi = 0; mi < 4; mi++) {
        int row = wm + mi * 16 + c;
        afh[mi] = *(const bf16x8*)(sAh + row * 64 + (((ks * 4 + g) ^ (row & 7)) * 8));
      }
      #pragma unroll
      for (int ni = 0; ni < 4; ni++) {
        int row = wn + ni * 16 + c;
        bfh[ni] = *(const bf16x8*)(sBh + row * 64 + (((ks * 4 + g) ^ (row & 7)) * 8));
      }
      #pragma unroll
      for (int mi = 0; mi < 4; mi++)
        #pragma unroll
        for (int ni = 0; ni < 4; ni++)
          acc[mi][ni] = __builtin_amdgcn_mfma_f32_16x16x32_bf16(afh[mi], bfh[ni], acc[mi][ni], 0, 0, 0);
    }
  }

  if (MODE == 0) {                       // QKV scatter
    #pragma unroll
    for (int mi = 0; mi < 4; mi++) {
      int grow0 = bm * 128 + wm + mi * 16 + g * 4;   // m = b*2048+s
      int b = grow0 >> 11, s0 = grow0 & 2047;
      #pragma unroll
      for (int ni = 0; ni < 4; ni++) {
        int gcol = bn * 128 + wn + ni * 16 + c;       // n in [0,3072)
        int which = gcol >> 10, rem = gcol & 1023;
        int hh = rem >> 6, dd = rem & 63;
        if (which == 2) {                              // V -> transposed [B,H,Dh,S]
          u16x4 hv;
          #pragma unroll
          for (int r = 0; r < 4; r++) hv[r] = f2bf(acc[mi][ni][r]);
          size_t off = ((size_t)((b * 16 + hh) * 64 + dd)) * 2048 + s0;
          *(u16x4*)(Vth + off) = hv;
        } else {                                       // Q or K -> [B,H,S,Dh]
          u16* dh = which ? Kh : Qh;
          float sc = which ? 1.0f : QSCALE;
          #pragma unroll
          for (int r = 0; r < 4; r++) {
            size_t off = ((size_t)(b * 16 + hh) * 2048 + (s0 + r)) * 64 + dd;
            dh[off] = f2bf(acc[mi][ni][r] * sc);
          }
        }
      }
    }
  } else {                               // out-proj: +bias, fp32
    #pragma unroll
    for (int mi = 0; mi < 4; mi++) {
      int grow0 = bm * 128 + wm + mi * 16 + g * 4;
      #pragma unroll
      for (int ni = 0; ni < 4; ni++) {
        int gcol = bn * 128 + wn + ni * 16 + c;
        float bb = bias[gcol];
        #pragma unroll
        for (int r = 0; r < 4; r++)
          Cout[(size_t)(grow0 + r) * 1024 + gcol] = acc[mi][ni][r] + bb;
      }
    }
  }
}

// ---------------- K3: block-causal flash attention (v9) ----------------
// grid (64 b*h, 16 qtiles desc); 512 threads = 8 waves, 16 q-rows/wave.
// KVBLK=128 (half the loop/barrier overhead per element). Swapped QK^T with
// the running max FOLDED INTO THE ACCUMULATOR INIT (C = -mrun): no subs, and
// the defer-check is just tl <= 8 (p bounded by 2^8; mrun starts at 0).
// exp2 via raw v_exp_f32. Row-sum via MFMA against a ones-vector (lsum lands
// in the same lane layout as O -> epilogue needs no cross-lane reduce).
// LDS: K 2x16KB + V 2x16KB = 64KB -> 2 blocks/CU.
__global__ __launch_bounds__(512, 4) void k_attn(
    const u16* __restrict__ Qh, const u16* __restrict__ Kh,
    const u16* __restrict__ Vth, u16* __restrict__ Oh) {
  __shared__ u16 lK[2][128 * 64], lV[2][64 * 128];
  const int t = threadIdx.x, lane = t & 63, w = t >> 6;  // 8 waves
  const int bh = blockIdx.x;             // 0..63
  const int qt = 15 - blockIdx.y;        // longest blocks dispatched first
  const int b = bh >> 4, h = bh & 15;
  const int qrow0 = qt * 128;
  const int kvlen = (qt / 2 + 1) * 256;
  const int g = lane >> 4, c = lane & 15;

  // Q fragments: wave w covers q-rows [qrow0 + w*16, +16); q = c as B-operand
  bf16x8 qf[2];
  {
    const u16* qb = Qh + ((size_t)bh * 2048 + qrow0 + w * 16) * 64;
    #pragma unroll
    for (int ks = 0; ks < 2; ks++)
      qf[ks] = *(const bf16x8*)(qb + (size_t)c * 64 + ks * 32 + g * 8);
  }

  const u16* Kb = Kh + (size_t)bh * 2048 * 64;
  const u16* Vb = Vth + (size_t)bh * 64 * 2048;

  // hoisted LDS read bases (XOR part is row-block independent):
  // K rows (128B): chunk = (ks*4+g) ^ (c&7);  V rows (256B): chunk = (ks*4+g) ^ c
  int kbase[2], vbase[4];
  #pragma unroll
  for (int ks = 0; ks < 2; ks++) kbase[ks] = c * 64 + (((ks * 4 + g) ^ (c & 7)) * 8);
  #pragma unroll
  for (int ks = 0; ks < 4; ks++) vbase[ks] = c * 128 + (((ks * 4 + g) ^ c) * 8);

  // staging: 512 threads x 2 chunks per tile per stream; source pre-swizzled.
  // K [128 kv][64 d]: chunk ci -> row ci>>3, col (ci&7)^(row&7); rows 64 apart
  // share the swizzle (64%8==0). V [64 d][128 kv]: row ci>>4, col (ci&15)^(row&15).
  const int kr0 = t >> 3, kcs0 = (t & 7) ^ (kr0 & 7);
  const int vr0 = t >> 4, vcs0 = (t & 15) ^ (vr0 & 15);

  const bf16x8 vones = {(short)0x3F80, (short)0x3F80, (short)0x3F80, (short)0x3F80,
                        (short)0x3F80, (short)0x3F80, (short)0x3F80, (short)0x3F80};

  float mrun = 0.f;                      // defer-max: p bounded by 2^8
  f32x4 lsum = {0.f, 0.f, 0.f, 0.f};     // row-sums, same layout as o rows
  f32x4 o[4] = {};                       // rows q = g*4 + r, col d = di*16+c

  const int ntiles = kvlen >> 7;

  // prologue: stage tile 0 into buffer 0
  gl16(Kb + (size_t)kr0 * 64 + kcs0 * 8, lK[0] + (size_t)t * 8);
  gl16(Kb + (size_t)(kr0 + 64) * 64 + kcs0 * 8, lK[0] + (size_t)(t + 512) * 8);
  gl16(Vb + (size_t)vr0 * 2048 + vcs0 * 8, lV[0] + (size_t)t * 8);
  gl16(Vb + (size_t)(vr0 + 32) * 2048 + vcs0 * 8, lV[0] + (size_t)(t + 512) * 8);
  __syncthreads();

  // prefetch pointers (tile 1), advanced by constant strides
  const u16* gK = Kb + (size_t)(128 + kr0) * 64 + kcs0 * 8;
  const u16* gV = Vb + (size_t)vr0 * 2048 + 128 + vcs0 * 8;

  for (int kt = 0; kt < ntiles; kt++) {
    const int cur = kt & 1, nxt = cur ^ 1;
    if (kt + 1 < ntiles) {               // prefetch next tile across compute
      gl16(gK, lK[nxt] + (size_t)t * 8);
      gl16(gK + 64 * 64, lK[nxt] + (size_t)(t + 512) * 8);
      gl16(gV, lV[nxt] + (size_t)t * 8);
      gl16(gV + 32 * 2048, lV[nxt] + (size_t)(t + 512) * 8);
      gK += 128 * 64;  gV += 128;
    }

    // S^T - mrun = mfma(A=K, B=Q, C=-mrun): lane holds q=c, kv=ni*16+g*4+r
    f32x4 s[8];
    #pragma unroll
    for (int ni = 0; ni < 8; ni++)
      s[ni] = (f32x4){-mrun, -mrun, -mrun, -mrun};
    __builtin_amdgcn_s_setprio(1);
    #pragma unroll
    for (int ni = 0; ni < 8; ni++)
      #pragma unroll
      for (int ks = 0; ks < 2; ks++) {
        bf16x8 kf = *(const bf16x8*)(lK[cur] + ni * 1024 + kbase[ks]);
        s[ni] = __builtin_amdgcn_mfma_f32_16x16x32_bf16(kf, qf[ks], s[ni], 0, 0, 0);
      }
    __builtin_amdgcn_s_setprio(0);

    // defer-max: lane-local partial max of the shifted scores
    float tl = fmaxf(fmaxf(fmaxf(fmax4(s[0]), fmax4(s[1])), fmaxf(fmax4(s[2]), fmax4(s[3]))),
                     fmaxf(fmaxf(fmax4(s[4]), fmax4(s[5])), fmaxf(fmax4(s[6]), fmax4(s[7]))));
    if (!__all(tl <= 8.0f)) {            // rare: large max jump
      float tm = fmaxf(tl, __shfl_xor(tl, 16));
      tm = fmaxf(tm, __shfl_xor(tm, 32));     // full row max across g-lanes
      float delta = fmaxf(tm, 0.0f);          // per-q (c-layout)
      mrun += delta;
      float al = fexp2(-delta);
      #pragma unroll
      for (int ni = 0; ni < 8; ni++)
        #pragma unroll
        for (int r = 0; r < 4; r++) s[ni][r] -= delta;
      #pragma unroll
      for (int r = 0; r < 4; r++) {
        float ar = __shfl(al, g * 4 + r);     // alpha for o-row q = g*4+r
        lsum[r] *= ar;
        #pragma unroll
        for (int di = 0; di < 4; di++) o[di][r] *= ar;
      }
    }

    // p = exp2(s) -> bf16 pack -> permlane -> PV A-frags (per ks, short lifetimes)
    bf16x8 pa[4];
    #pragma unroll
    for (int ks = 0; ks < 4; ks++) {
      unsigned int e0 = cvtpk(fexp2(s[2 * ks][0]), fexp2(s[2 * ks][1]));
      unsigned int e1 = cvtpk(fexp2(s[2 * ks][2]), fexp2(s[2 * ks][3]));
      unsigned int f0 = cvtpk(fexp2(s[2 * ks + 1][0]), fexp2(s[2 * ks + 1][1]));
      unsigned int f1 = cvtpk(fexp2(s[2 * ks + 1][2]), fexp2(s[2 * ks + 1][3]));
      asm volatile("v_permlane32_swap_b32 %0, %1" : "+v"(e0), "+v"(f0));
      asm volatile("v_permlane16_swap_b32 %0, %1" : "+v"(e0), "+v"(f0));
      asm volatile("v_permlane32_swap_b32 %0, %1" : "+v"(e1), "+v"(f1));
      asm volatile("v_permlane16_swap_b32 %0, %1" : "+v"(e1), "+v"(f1));
      union { u32x4 u; bf16x8 bv; } cvu;
      cvu.u = (u32x4){e0, e1, f0, f1};
      pa[ks] = cvu.bv;                   // P[q=c, kv=ks*32+g*8+j], j=0..7
    }

    // PV: O += P * V; row-sum via ones-MFMA (lands in o's lane layout)
    __builtin_amdgcn_s_setprio(1);
    #pragma unroll
    for (int di = 0; di < 4; di++)
      #pragma unroll
      for (int ks = 0; ks < 4; ks++) {
        bf16x8 vf = *(const bf16x8*)(lV[cur] + di * 2048 + vbase[ks]);
        o[di] = __builtin_amdgcn_mfma_f32_16x16x32_bf16(pa[ks], vf, o[di], 0, 0, 0);
      }
    #pragma unroll
    for (int ks = 0; ks < 4; ks++)
      lsum = __builtin_amdgcn_mfma_f32_16x16x32_bf16(pa[ks], vones, lsum, 0, 0, 0);
    __builtin_amdgcn_s_setprio(0);

    // drains the prefetch (issued ~1k cycles ago) and fences buffer reuse
    __syncthreads();
  }

  // epilogue: normalize (lsum already in o layout), write attnout bf16
  #pragma unroll
  for (int r = 0; r < 4; r++) {
    float ir = 1.0f / lsum[r];
    int srow = qrow0 + w * 16 + g * 4 + r;
    size_t rowo = ((size_t)b * 2048 + srow) * 1024 + h * 64;
    #pragma unroll
    for (int di = 0; di < 4; di++)
      Oh[rowo + di * 16 + c] = f2bf(o[di][r] * ir);
  }
}

// ---------------- launch ----------------
extern "C" void kernel_launch(void* const* d_in, const int* in_sizes, int n_in,
                              void* d_out, int out_size, void* d_ws, size_t ws_size,
                              hipStream_t stream) {
  const float* x     = (const float*)d_in[0];
  const float* gamma = (const float*)d_in[1];
  const float* beta  = (const float*)d_in[2];
  const float* Wqkv  = (const float*)d_in[3];
  const float* Wout  = (const float*)d_in[4];
  const float* bout  = (const float*)d_in[5];
  float* out = (float*)d_out;

  char* ws = (char*)d_ws;
  size_t off = 0;
  auto alloc = [&](size_t bytes) { char* p = ws + off; off += (bytes + 255) & ~(size_t)255; return p; };
  const size_t SZ_XN = (size_t)8192 * 1024 * 2;         // 16MB
  const size_t SZ_WQ = (size_t)3072 * 1024 * 2;         // 6MB
  const size_t SZ_WO = (size_t)1024 * 1024 * 2;         // 2MB
  const size_t SZ_QKV = (size_t)4 * 16 * 2048 * 64 * 2; // 16MB
  u16* xnh  = (u16*)alloc(SZ_XN);   // also attnout (bf16) after attention
  u16* wqth = (u16*)alloc(SZ_WQ);
  u16* woth = (u16*)alloc(SZ_WO);
  u16* Qh  = (u16*)alloc(SZ_QKV);
  u16* Kh  = (u16*)alloc(SZ_QKV);
  u16* Vth = (u16*)alloc(SZ_QKV);
  if (off > ws_size) return;  // workspace too small -> fail visibly (poisoned out)

  k_ln_split<<<8192, 256, 0, stream>>>(x, gamma, beta, xnh);
  k_wsplit_t<<<dim3(96, 32), 256, 0, stream>>>(Wqkv, wqth, 1024, 3072);
  k_wsplit_t<<<dim3(32, 32), 256, 0, stream>>>(Wout, woth, 1024, 1024);
  // QKV projection: one pure-bf16 GEMM over all 3072 columns
  k_gemm<0><<<dim3(64, 24), 256, 0, stream>>>(xnh, wqth,
                                              Qh, Kh, Vth, nullptr, nullptr);
  // attnout (bf16) reuses the xn buffer (xn is dead after the QKV GEMM)
  k_attn<<<dim3(64, 16), 512, 0, stream>>>(Qh, Kh, Vth, xnh);
  k_gemm<1><<<dim3(64, 8), 256, 0, stream>>>(xnh, woth,
                                             nullptr, nullptr, nullptr,
                                             out, bout);
}